// Round 13
// baseline (8877.589 us; speedup 1.0000x reference)
//
#include <hip/hip_runtime.h>
#include <math.h>

// Problem constants (fixed by reference)
#define T   1024
#define NB  16
#define HD  512

// ws layout (float offsets)
#define OFF_BAR  0                         // 2048 ints: flag[2 dir][4 bgrp][32 uslice][8 wave]
#define OFF_HH   2048                      // h_hist [2][T][NB][HD] = 16,777,216 floats
#define OFF_SH   (OFF_HH + 16777216)       // SH [16384][512] = 8,388,608 floats
#define OFF_SEGP (OFF_SH + 8388608)        // [16384]
#define OFF_GCTX (OFF_SEGP + 16384)        // [16][1024]
#define OFF_SEL  (OFF_GCTX + 16384)        // ints [16][12]

typedef unsigned long long u64;

__device__ __forceinline__ float sigmoidf_(float x){ return 1.0f/(1.0f + __expf(-x)); }
// fast tanh via exp2-based __expf; |err| ~1e-7, graceful saturation at +/-1
__device__ __forceinline__ float tanhf_(float x){ return 1.0f - 2.0f/(1.0f + __expf(2.0f*x)); }

// ---------------------------------------------------------------------------
// Persistent bidirectional LSTM, ZERO-BARRIER WAVES. grid=256, block=512.
// wg -> (dir = wg&1, bgrp = (wg>>1)&3 : 4 batches, uslice = wg>>3 : 16 units).
// Wave wid owns units U+2*wid, U+2*wid+1 with ALL FOUR GATES IN-WAVE
// (rows r = gate*2+ui, r5-verified) -> gate gather = 3 shfl_xor (8/4/12).
// Each wave is a fully independent agent: x-proj -> poll (4 flags/lane over
// the domain's 256 per-wave flags) -> plain cached h loads (L1-amortized
// across the CU) -> h-proj -> 5-stage reduce-scatter -> in-wave gates ->
// paired 8B sc1 h-store -> vmcnt(0) -> per-wave flag.
// NO __syncthreads, NO LDS in the loop. This removes r8/r10/r12's per-step
// block coupling (2 barriers + gbuf LDS RT + wave0-serial gates ~1us/step).
// Skew self-bounds at 1 step via the 256-flag AND. All primitives proven:
// r5 gate-shfl, r8 sc1-store+vmcnt+flag+plain-h-read, r2 u64 atomic store.
// ---------------------------------------------------------------------------
__global__ __launch_bounds__(512, 1)
void lstm_kernel(const int* __restrict__ instr, const float* __restrict__ emb,
                 const float* __restrict__ wih_f, const float* __restrict__ whh_f,
                 const float* __restrict__ bih_f, const float* __restrict__ bhh_f,
                 const float* __restrict__ wih_b, const float* __restrict__ whh_b,
                 const float* __restrict__ bih_b, const float* __restrict__ bhh_b,
                 float* __restrict__ ws)
{
    float* h_hist = ws + OFF_HH;
    int* flags = (int*)ws;            // [2][4][32][8]

    const int wg     = blockIdx.x;    // 0..255
    const int dir    = wg & 1;
    const int bgrp   = (wg >> 1) & 3; // batches bgrp*4..+3
    const int uslice = wg >> 3;       // 0..31
    const int U      = uslice * 16;   // 16 units per wg (2 per wave)
    const int b0     = bgrp * 4;

    int* barf = flags + (dir*4 + bgrp)*256;   // domain: 32 wgs x 8 waves

    const float* wih = dir ? wih_b : wih_f;
    const float* whh = dir ? whh_b : whh_f;
    const float* bih = dir ? bih_b : bih_f;
    const float* bhh = dir ? bhh_b : bhh_f;

    const int tid  = threadIdx.x;
    const int wid  = tid >> 6;        // 0..7: owns units U+2*wid, U+2*wid+1
    const int lane = tid & 63;        // k-chunk id (8 k's per lane)

    // Weight slices: 8 rows (4 gates x 2 units), row r = gate*2 + ui
    float wi[64], wh[64];
#pragma unroll
    for (int ri = 0; ri < 8; ++ri){
        int gate = ri >> 1, ui = ri & 1;
        size_t row = (size_t)(gate*HD + U + wid*2 + ui) * HD + lane*8;
        float4 a0 = *(const float4*)(wih + row);
        float4 a1 = *(const float4*)(wih + row + 4);
        float4 b0v = *(const float4*)(whh + row);
        float4 b1v = *(const float4*)(whh + row + 4);
        wi[ri*8+0]=a0.x; wi[ri*8+1]=a0.y; wi[ri*8+2]=a0.z; wi[ri*8+3]=a0.w;
        wi[ri*8+4]=a1.x; wi[ri*8+5]=a1.y; wi[ri*8+6]=a1.z; wi[ri*8+7]=a1.w;
        wh[ri*8+0]=b0v.x; wh[ri*8+1]=b0v.y; wh[ri*8+2]=b0v.z; wh[ri*8+3]=b0v.w;
        wh[ri*8+4]=b1v.x; wh[ri*8+5]=b1v.y; wh[ri*8+6]=b1v.z; wh[ri*8+7]=b1v.w;
    }

    // reduce-scatter ownership: lane holds value j = bitrev5(lane&31),
    // j = bi*8 + gate*2 + ui. Owners = gate==0 holders in low half.
    const int j0 = ((lane&1)<<4)|((lane&2)<<2)|(lane&4)|((lane&8)>>2)|((lane&16)>>4);
    const bool own = ((lane & 12) == 0) && (lane < 32);
    const int own_bi = j0 >> 3;
    const int own_ui = j0 & 1;
    const int own_u  = U + wid*2 + own_ui;   // well-defined on all lanes
    const int own_b  = b0 + own_bi;

    const float bI = bih[0*HD + own_u] + bhh[0*HD + own_u];
    const float bF = bih[1*HD + own_u] + bhh[1*HD + own_u];
    const float bG = bih[2*HD + own_u] + bhh[2*HD + own_u];
    const float bO = bih[3*HD + own_u] + bhh[3*HD + own_u];
    float cst = 0.0f;

    const u64* fb = (const u64*)barf;

    for (int s = 0; s < T; ++s){
        const int tp = dir ? (T-1-s) : s;   // original-time index

        // ---- x gather + x-projection (issued before the poll; flies during it)
        float a[32];
#pragma unroll
        for (int j = 0; j < 32; ++j) a[j] = 0.0f;

#pragma unroll
        for (int bi = 0; bi < 4; ++bi){
            int b = b0 + bi;
            int idx = instr[b*T + tp];
            const float* px = emb + (size_t)idx*HD + lane*8;
            float4 x0 = *(const float4*)px;
            float4 x1 = *(const float4*)(px + 4);
            float xs[8] = {x0.x,x0.y,x0.z,x0.w,x1.x,x1.y,x1.z,x1.w};
#pragma unroll
            for (int kk = 0; kk < 8; ++kk){
                float xv = xs[kk];
#pragma unroll
                for (int ri = 0; ri < 8; ++ri)
                    a[bi*8+ri] = fmaf(xv, wi[ri*8+kk], a[bi*8+ri]);
            }
        }

        if (s > 0){
            // ---- per-wave poll: 4 flags per lane (2 u64), 256 flags/domain
            for (;;){
                u64 q0 = __hip_atomic_load(fb + lane*2,     __ATOMIC_RELAXED, __HIP_MEMORY_SCOPE_AGENT);
                u64 q1 = __hip_atomic_load(fb + lane*2 + 1, __ATOMIC_RELAXED, __HIP_MEMORY_SCOPE_AGENT);
                bool ok = ((int)(q0      ) >= s) && ((int)(q0 >> 32) >= s)
                       && ((int)(q1      ) >= s) && ((int)(q1 >> 32) >= s);
                if (__all(ok)) break;
                __builtin_amdgcn_s_sleep(1);
            }

            // ---- h loads (plain cached; 8 waves read same 4 vectors -> L1 hits)
            const int tprev = dir ? (T - s) : (s - 1);
            const float* hbase = h_hist + (size_t)(dir*T + tprev)*NB*HD;
#pragma unroll
            for (int bi = 0; bi < 4; ++bi){
                const float* ph = hbase + (size_t)(b0+bi)*HD + lane*8;
                float4 h0 = *(const float4*)ph;
                float4 h1 = *(const float4*)(ph + 4);
                float hs[8] = {h0.x,h0.y,h0.z,h0.w,h1.x,h1.y,h1.z,h1.w};
#pragma unroll
                for (int kk = 0; kk < 8; ++kk){
                    float hv = hs[kk];
#pragma unroll
                    for (int ri = 0; ri < 8; ++ri)
                        a[bi*8+ri] = fmaf(hv, wh[ri*8+kk], a[bi*8+ri]);
                }
            }
        }

        // ---- reduce-scatter: 32 values over 64 lanes (5 stages + merge)
#pragma unroll
        for (int m = 0; m < 5; ++m){
            const int half = 16 >> m;
            const bool up = (lane >> m) & 1;
#pragma unroll
            for (int j = 0; j < 16; ++j){
                if (j < half){
                    float lo = a[j], hi = a[j+half];
                    float rlo = __shfl_xor(lo, 1<<m, 64);
                    float rhi = __shfl_xor(hi, 1<<m, 64);
                    a[j] = up ? (hi + rhi) : (lo + rlo);
                }
            }
        }
        a[0] += __shfl_xor(a[0], 32, 64);   // cross-half k merge

        // ---- in-wave gate gather: i@L, f@L^8, g@L^4, o@L^12 (r5-verified)
        float vi = a[0];
        float vf = __shfl_xor(vi, 8, 64);
        float vg = __shfl_xor(vi, 4, 64);
        float vo = __shfl_xor(vi, 12, 64);

        float iv = sigmoidf_(vi + bI);
        float fv = sigmoidf_(vf + bF);
        float gv = tanhf_  (vg + bG);
        float ov = sigmoidf_(vo + bO);
        cst = fv*cst + iv*gv;                 // garbage on non-owner lanes (unused)
        float hv = ov * tanhf_(cst);

        // pair the 2 units of this wave into one 8B sc1 store (ui=0 lane stores)
        float hv2 = __shfl_xor(hv, 16, 64);   // partner lane: same bi, ui^1
        if (own && own_ui == 0){
            float2 pr = make_float2(hv, hv2);
            __hip_atomic_store(
                (u64*)&h_hist[((size_t)(dir*T + tp)*NB + own_b)*HD + U + wid*2],
                __builtin_bit_cast(u64, pr), __ATOMIC_RELAXED, __HIP_MEMORY_SCOPE_AGENT);
        }

        // per-wave producer tail: ack own stores, post own flag
        asm volatile("s_waitcnt vmcnt(0)" ::: "memory");
        __builtin_amdgcn_sched_barrier(0);
        if (lane == 0)
            __hip_atomic_store(barf + uslice*8 + wid, s + 1,
                               __ATOMIC_RELAXED, __HIP_MEMORY_SCOPE_AGENT);
    }
}

// ---------------------------------------------------------------------------
// SH = relu(enc @ ws1.T + bs1)   M=16384 N=512 K=1024, fp32 64x64x16 tiles
// ---------------------------------------------------------------------------
__global__ __launch_bounds__(256, 2)
void seg_gemm(const float* __restrict__ ws_, const float* __restrict__ ws1,
              const float* __restrict__ bs1)
{
    const float* h_hist = ws_ + OFF_HH;
    float* SH = (float*)(ws_ + OFF_SH);
    __shared__ float As[64][17];
    __shared__ float Bs[64][17];
    const int m0 = blockIdx.x * 64;
    const int n0 = blockIdx.y * 64;
    const int tid = threadIdx.x;
    const int r  = tid >> 2;
    const int kq = (tid & 3) * 4;
    const int ty = tid >> 4, tx = tid & 15;
    const int bI = m0 >> 10;          // tile stays inside one batch
    const int t0 = m0 & 1023;

    float acc[4][4];
#pragma unroll
    for (int i=0;i<4;i++)
#pragma unroll
        for (int j=0;j<4;j++) acc[i][j]=0.0f;

    for (int kb = 0; kb < 1024; kb += 16){
        int kk = kb + kq;
        const float* ap = (kk < 512)
            ? h_hist + ((size_t)(t0 + r)*NB + bI)*HD + kk
            : h_hist + ((size_t)(T + t0 + r)*NB + bI)*HD + (kk - 512);
        float4 av = *(const float4*)ap;
        As[r][kq+0]=av.x; As[r][kq+1]=av.y; As[r][kq+2]=av.z; As[r][kq+3]=av.w;
        float4 bv = *(const float4*)(ws1 + (size_t)(n0 + r)*1024 + kk);
        Bs[r][kq+0]=bv.x; Bs[r][kq+1]=bv.y; Bs[r][kq+2]=bv.z; Bs[r][kq+3]=bv.w;
        __syncthreads();
#pragma unroll
        for (int k2 = 0; k2 < 16; ++k2){
            float av_[4], bv_[4];
#pragma unroll
            for (int i=0;i<4;i++) av_[i] = As[ty*4+i][k2];
#pragma unroll
            for (int j=0;j<4;j++) bv_[j] = Bs[tx*4+j][k2];
#pragma unroll
            for (int i=0;i<4;i++)
#pragma unroll
                for (int j=0;j<4;j++) acc[i][j] = fmaf(av_[i], bv_[j], acc[i][j]);
        }
        __syncthreads();
    }
#pragma unroll
    for (int i=0;i<4;i++){
        int m = m0 + ty*4 + i;
#pragma unroll
        for (int j=0;j<4;j++){
            int n = n0 + tx*4 + j;
            SH[(size_t)m*512 + n] = fmaxf(acc[i][j] + bs1[n], 0.0f);
        }
    }
}

// ---------------------------------------------------------------------------
// scores -> sigmoid -> seg_probs (ws copy + d_out)
// ---------------------------------------------------------------------------
__global__ void seg_score(const float* __restrict__ ws_, const float* __restrict__ ws2,
                          const float* __restrict__ bs2, float* __restrict__ dout)
{
    const float* SH = ws_ + OFF_SH;
    float* segp = (float*)(ws_ + OFF_SEGP);
    int row  = blockIdx.x*4 + (threadIdx.x >> 6);
    int lane = threadIdx.x & 63;
    const float* p = SH + (size_t)row*512 + lane*8;
    const float* q = ws2 + lane*8;
    float4 a0=*(const float4*)p, a1=*(const float4*)(p+4);
    float4 b0=*(const float4*)q, b1=*(const float4*)(q+4);
    float ssum = a0.x*b0.x + a0.y*b0.y + a0.z*b0.z + a0.w*b0.w
               + a1.x*b1.x + a1.y*b1.y + a1.z*b1.z + a1.w*b1.w;
#pragma unroll
    for (int m=1;m<64;m<<=1) ssum += __shfl_xor(ssum, m, 64);
    if (lane == 0){
        float z = ssum + bs2[0];
        float pr = 1.0f/(1.0f + __expf(-z));
        segp[row] = pr;
        dout[81920 + row] = pr;
    }
}

// ---------------------------------------------------------------------------
// Per-batch: mask scan (count, first-10 idx), pooled -> gctx
// ---------------------------------------------------------------------------
__global__ void select_gctx(float* __restrict__ ws_, const float* __restrict__ wgm,
                            const float* __restrict__ bgv)
{
    const float* h_hist = ws_ + OFF_HH;
    const float* segp   = ws_ + OFF_SEGP;
    float* gctx = ws_ + OFF_GCTX;
    int* sel = (int*)(ws_ + OFF_SEL);
    int b = blockIdx.x, tid = threadIdx.x;
    __shared__ unsigned char flag[1024];
    __shared__ float pool[1024];
    for (int j = tid; j < 1024; j += 256){
        flag[j] = segp[b*1024 + j] > 0.5f ? 1 : 0;
        pool[j] = (j < 512) ? h_hist[((size_t)1023*NB + b)*HD + j]
                            : h_hist[((size_t)T*NB + b)*HD + (j - 512)];
    }
    __syncthreads();
    if (tid == 0){
        int c = 0;
        int tmp[10];
        for (int j = 0; j < 10; ++j) tmp[j] = 0;
        for (int t = 0; t < 1024; ++t){
            if (flag[t]){ if (c < 10) tmp[c] = t; c++; }
        }
        for (int j = 0; j < 10; ++j) sel[b*12 + j] = tmp[j];
        sel[b*12 + 10] = c;
        sel[b*12 + 11] = 0;
    }
    __syncthreads();
    for (int n = tid; n < 1024; n += 256){
        float acc = bgv[n];
        const float* wr = wgm + (size_t)n*1024;
        for (int k = 0; k < 1024; k += 4){
            acc += wr[k]*pool[k] + wr[k+1]*pool[k+1] + wr[k+2]*pool[k+2] + wr[k+3]*pool[k+3];
        }
        gctx[b*1024 + n] = acc;
    }
}

// ---------------------------------------------------------------------------
// Decoder: one block per (b,slot)
// ---------------------------------------------------------------------------
__global__ void decode(const float* __restrict__ ws_, const float* __restrict__ wd1,
                       const float* __restrict__ bd1, const float* __restrict__ wd2,
                       const float* __restrict__ bd2, float* __restrict__ dout)
{
    const float* h_hist = ws_ + OFF_HH;
    const float* gctx   = ws_ + OFF_GCTX;
    const int* sel = (const int*)(ws_ + OFF_SEL);
    int blk = blockIdx.x;
    int b = blk / 10, slot = blk % 10;
    int tid = threadIdx.x;
    int count = sel[b*12 + 10];
    int nval = count < 10 ? count : 10;
    bool empty = (count == 0);
    float* outp = dout + (size_t)(b*10 + slot)*512;
    if (slot >= nval && !(empty && slot == 0)){
        for (int n = tid; n < 512; n += 256) outp[n] = 0.0f;
        return;
    }
    __shared__ float row[1024];
    __shared__ float dh[512];
    if (empty){
        for (int j = tid; j < 1024; j += 256) row[j] = gctx[b*1024 + j];
    } else {
        int t = sel[b*12 + slot];
        for (int j = tid; j < 1024; j += 256)
            row[j] = (j < 512) ? h_hist[((size_t)t*NB + b)*HD + j]
                               : h_hist[((size_t)(T + t)*NB + b)*HD + (j-512)];
    }
    __syncthreads();
    for (int d = tid; d < 512; d += 256){
        float acc = bd1[d];
        const float* wr = wd1 + (size_t)d*1024;
        for (int k = 0; k < 1024; ++k) acc += wr[k]*row[k];
        dh[d] = fmaxf(acc, 0.0f);
    }
    __syncthreads();
    for (int n = tid; n < 512; n += 256){
        float acc = bd2[n];
        const float* wr = wd2 + (size_t)n*512;
        for (int k = 0; k < 512; ++k) acc += wr[k]*dh[k];
        outp[n] = acc;
    }
}

extern "C" void kernel_launch(void* const* d_in, const int* in_sizes, int n_in,
                              void* d_out, int out_size, void* d_ws, size_t ws_size,
                              hipStream_t stream)
{
    const int*   instr = (const int*)d_in[0];
    const float* emb   = (const float*)d_in[1];
    const float* wih_f = (const float*)d_in[2];
    const float* whh_f = (const float*)d_in[3];
    const float* bih_f = (const float*)d_in[4];
    const float* bhh_f = (const float*)d_in[5];
    const float* wih_b = (const float*)d_in[6];
    const float* whh_b = (const float*)d_in[7];
    const float* bih_b = (const float*)d_in[8];
    const float* bhh_b = (const float*)d_in[9];
    const float* wg_   = (const float*)d_in[10];
    const float* bg_   = (const float*)d_in[11];
    const float* ws1   = (const float*)d_in[12];
    const float* bs1   = (const float*)d_in[13];
    const float* ws2   = (const float*)d_in[14];
    const float* bs2   = (const float*)d_in[15];
    const float* wd1   = (const float*)d_in[16];
    const float* bd1   = (const float*)d_in[17];
    const float* wd2   = (const float*)d_in[18];
    const float* bd2   = (const float*)d_in[19];
    float* out = (float*)d_out;
    float* ws  = (float*)d_ws;

    // zero the per-wave step flags (captured as a memset node; re-runs every replay)
    hipMemsetAsync(d_ws, 0, 8192, stream);

    hipLaunchKernelGGL(lstm_kernel, dim3(256), dim3(512), 0, stream,
                       instr, emb, wih_f, whh_f, bih_f, bhh_f,
                       wih_b, whh_b, bih_b, bhh_b, ws);
    hipLaunchKernelGGL(seg_gemm, dim3(256, 8), dim3(256), 0, stream, ws, ws1, bs1);
    hipLaunchKernelGGL(seg_score, dim3(4096), dim3(256), 0, stream, ws, ws2, bs2, out);
    hipLaunchKernelGGL(select_gctx, dim3(16), dim3(256), 0, stream, ws, wg_, bg_);
    hipLaunchKernelGGL(decode, dim3(160), dim3(256), 0, stream, ws, wd1, bd1, wd2, bd2, out);
}